// Round 1
// baseline (1182.165 us; speedup 1.0000x reference)
//
#include <hip/hip_runtime.h>
#include <math.h>

#define B_SZ 64
#define T_SZ 512
#define E_SZ 300
#define M_TOT (B_SZ * T_SZ)   // 32768 tokens

// =====================================================================
// GEMM: C[M,300] = act(A[M,300] @ W[0:300,0:300-slice].T + bias)
// W row j lives at W + j*wstride (wstride=300 for fc1/l2, 600 for l1 x-part)
// GATHER: A row m is emb[idx[m], :]
// Tiles: 64(M) x 64(N), K-chunks of 12 (300 = 25*12). Block = 256 threads.
// =====================================================================
template<bool GATHER, bool RELU>
__global__ __launch_bounds__(256) void gemm300(
    const float* __restrict__ A, const int* __restrict__ idx,
    const float* __restrict__ W, int wstride,
    const float* __restrict__ bias,
    float* __restrict__ C)
{
    __shared__ float As[12][64];
    __shared__ float Bs[12][64];

    const int tid = threadIdx.x;
    const int m0 = blockIdx.x * 64;
    const int n0 = blockIdx.y * 64;

    // ---- loader setup (threads 0..191: one float4 of A and one of B per k-chunk)
    const float* aptr = nullptr;
    const float* bptr = nullptr;
    bool bvalid = false;
    int m_l = 0, kq = 0;
    if (tid < 192) {
        m_l = tid / 3;          // 0..63
        kq  = tid % 3;          // 0..2  -> k offset kq*4
        long row = GATHER ? (long)idx[m0 + m_l] : (long)(m0 + m_l);
        aptr = A + row * 300 + kq * 4;
        int j = n0 + m_l;       // weight row (output column)
        bvalid = (j < 300);
        if (bvalid) bptr = W + (long)j * wstride + kq * 4;
    }

    const int ty = tid >> 4;    // 0..15 -> m sub-tile
    const int tx = tid & 15;    // 0..15 -> n sub-tile

    float acc[4][4] = {};

    for (int k0 = 0; k0 < 300; k0 += 12) {
        float4 av = make_float4(0.f, 0.f, 0.f, 0.f);
        float4 bv = make_float4(0.f, 0.f, 0.f, 0.f);
        if (tid < 192) {
            av = *(const float4*)(aptr + k0);
            if (bvalid) bv = *(const float4*)(bptr + k0);
        }
        __syncthreads();   // previous compute done before overwriting tiles
        if (tid < 192) {
            As[kq * 4 + 0][m_l] = av.x;
            As[kq * 4 + 1][m_l] = av.y;
            As[kq * 4 + 2][m_l] = av.z;
            As[kq * 4 + 3][m_l] = av.w;
            Bs[kq * 4 + 0][m_l] = bv.x;
            Bs[kq * 4 + 1][m_l] = bv.y;
            Bs[kq * 4 + 2][m_l] = bv.z;
            Bs[kq * 4 + 3][m_l] = bv.w;
        }
        __syncthreads();

        #pragma unroll
        for (int kk = 0; kk < 12; kk++) {
            float4 a4 = *(const float4*)&As[kk][ty * 4];
            float4 b4 = *(const float4*)&Bs[kk][tx * 4];
            float a[4] = {a4.x, a4.y, a4.z, a4.w};
            float b[4] = {b4.x, b4.y, b4.z, b4.w};
            #pragma unroll
            for (int im = 0; im < 4; im++)
                #pragma unroll
                for (int in = 0; in < 4; in++)
                    acc[im][in] += a[im] * b[in];
        }
    }

    // ---- epilogue: bias (+ReLU), guarded store
    float bsv[4];
    #pragma unroll
    for (int in = 0; in < 4; in++) {
        int n = n0 + tx * 4 + in;
        bsv[in] = (n < 300) ? bias[n] : 0.f;
    }
    const int nbase = n0 + tx * 4;
    #pragma unroll
    for (int im = 0; im < 4; im++) {
        long m = m0 + ty * 4 + im;
        float v[4];
        #pragma unroll
        for (int in = 0; in < 4; in++) {
            float x = acc[im][in] + bsv[in];
            if (RELU) x = fmaxf(x, 0.f);
            v[in] = x;
        }
        if (nbase + 3 < 300) {
            *(float4*)&C[m * 300 + nbase] = make_float4(v[0], v[1], v[2], v[3]);
        } else {
            #pragma unroll
            for (int in = 0; in < 4; in++)
                if (nbase + in < 300) C[m * 300 + nbase + in] = v[in];
        }
    }
}

// =====================================================================
// RNN: one workgroup per batch element. Wh = l1_w[:, 300:600] held in
// registers: 900 active threads, thread (j,s) holds Wh[j, s*100:(s+1)*100].
// hid_out written in-place over xpart (same thread reads & writes addr).
// =====================================================================
__global__ __launch_bounds__(1024) void rnn_kernel(
    const float* __restrict__ xpart,   // [B, T, 300] (= l1 x-part + l1_b)
    const float* __restrict__ l1_w,    // [300, 600]
    float* __restrict__ hid_out)       // [B, T, 300] (may alias xpart)
{
    const int b   = blockIdx.x;
    const int tid = threadIdx.x;

    __shared__ float hid[304];       // current hidden state (300 used)
    __shared__ float partial[904];   // 900 partial dot products

    // ---- preload weights into registers
    float4 w4[25];
    int j = 0, s = 0;
    const bool active = (tid < 900);
    if (active) {
        j = tid / 3;
        s = tid % 3;
        const float4* wr = (const float4*)(l1_w + (long)j * 600 + 300 + s * 100);
        #pragma unroll
        for (int i = 0; i < 25; i++) w4[i] = wr[i];
    }

    if (tid < 300) hid[tid] = 0.f;   // hidden0 = zeros
    __syncthreads();

    const long base = (long)b * T_SZ * 300;

    for (int t = 0; t < T_SZ; t++) {
        // issue the xpart load early; consumed after the dot loop
        float xp = 0.f;
        if (tid < 300) xp = xpart[base + (long)t * 300 + tid];

        if (active) {
            const float4* hv = (const float4*)&hid[s * 100];
            float acc = 0.f;
            #pragma unroll
            for (int i = 0; i < 25; i++) {
                float4 h4 = hv[i];
                acc += w4[i].x * h4.x + w4[i].y * h4.y
                     + w4[i].z * h4.z + w4[i].w * h4.w;
            }
            partial[tid] = acc;
        }
        __syncthreads();

        if (tid < 300) {
            float y = xp + partial[3 * tid] + partial[3 * tid + 1] + partial[3 * tid + 2];
            float h = 1.f / (1.f + __expf(-y));
            hid_out[base + (long)t * 300 + tid] = h;
            hid[tid] = h;
        }
        __syncthreads();
    }
}

// =====================================================================
// Max-pool over time + fc2: out[b, 0:2]
// =====================================================================
__global__ __launch_bounds__(256) void pool_fc2(
    const float* __restrict__ outs,    // [B, T, 300]
    const float* __restrict__ fc2_w,   // [2, 300]
    const float* __restrict__ fc2_b,   // [2]
    float* __restrict__ out)           // [B, 2]
{
    const int b   = blockIdx.x;
    const int tid = threadIdx.x;
    __shared__ float pooled[304];

    const long base = (long)b * T_SZ * 300;
    for (int jj = tid; jj < 300; jj += 256) {
        float m = -3.4e38f;
        #pragma unroll 8
        for (int t = 0; t < T_SZ; t++)
            m = fmaxf(m, outs[base + (long)t * 300 + jj]);
        pooled[jj] = m;
    }
    __syncthreads();

    const int o    = tid >> 6;   // wave id 0..3
    const int lane = tid & 63;
    if (o < 2) {
        float sacc = 0.f;
        for (int jj = lane; jj < 300; jj += 64)
            sacc += pooled[jj] * fc2_w[o * 300 + jj];
        #pragma unroll
        for (int off = 32; off > 0; off >>= 1)
            sacc += __shfl_down(sacc, off);
        if (lane == 0) out[b * 2 + o] = sacc + fc2_b[o];
    }
}

// =====================================================================
extern "C" void kernel_launch(void* const* d_in, const int* in_sizes, int n_in,
                              void* d_out, int out_size, void* d_ws, size_t ws_size,
                              hipStream_t stream)
{
    const int*   x     = (const int*)  d_in[0];   // [64, 512]
    const float* emb   = (const float*)d_in[1];   // [100000, 300]
    const float* fc1_w = (const float*)d_in[2];   // [300, 300]
    const float* fc1_b = (const float*)d_in[3];   // [300]
    const float* l1_w  = (const float*)d_in[4];   // [300, 600]
    const float* l1_b  = (const float*)d_in[5];   // [300]
    const float* l2_w  = (const float*)d_in[6];   // [300, 300]
    const float* l2_b  = (const float*)d_in[7];   // [300]
    const float* fc2_w = (const float*)d_in[8];   // [2, 300]
    const float* fc2_b = (const float*)d_in[9];   // [2]
    float* out = (float*)d_out;

    // workspace: buf0 = h (then outs), buf1 = xpart (then hid, in-place)
    float* buf0 = (float*)d_ws;
    float* buf1 = buf0 + (size_t)M_TOT * 300;

    dim3 gg(M_TOT / 64, 5), gb(256);

    // K1: h = relu(emb[x] @ fc1_w.T + fc1_b)
    gemm300<true,  true ><<<gg, gb, 0, stream>>>(emb,  x,       fc1_w, 300, fc1_b, buf0);
    // K2: xpart = h @ l1_w[:, :300].T + l1_b
    gemm300<false, false><<<gg, gb, 0, stream>>>(buf0, nullptr, l1_w,  600, l1_b,  buf1);
    // K3: sequential RNN (in-place xpart -> hidden states)
    rnn_kernel<<<B_SZ, 1024, 0, stream>>>(buf1, l1_w, buf1);
    // K4: outs = hid @ l2_w.T + l2_b
    gemm300<false, false><<<gg, gb, 0, stream>>>(buf1, nullptr, l2_w,  300, l2_b,  buf0);
    // K5: max over t, then fc2
    pool_fc2<<<B_SZ, gb, 0, stream>>>(buf0, fc2_w, fc2_b, out);
}

// Round 2
// 758.819 us; speedup vs baseline: 1.5579x; 1.5579x over previous
//
#include <hip/hip_runtime.h>
#include <hip/hip_fp16.h>
#include <math.h>

#define B_SZ 64
#define T_SZ 512
#define E_SZ 300
#define M_TOT (B_SZ * T_SZ)   // 32768 tokens
#define HSTR  152             // row stride (uints) of packed-f16x2 buffers (150 used)

typedef _Float16 h2_t __attribute__((ext_vector_type(2)));

// f16-pair dot with fp32 accumulate: c + a.x*b.x + a.y*b.y
__device__ __forceinline__ float dot2(unsigned int a, unsigned int b, float c) {
#if __has_builtin(__builtin_amdgcn_fdot2)
    h2_t ah = __builtin_bit_cast(h2_t, a);
    h2_t bh = __builtin_bit_cast(h2_t, b);
    return __builtin_amdgcn_fdot2(ah, bh, c, false);
#else
    __half2 ah = __builtin_bit_cast(__half2, a);
    __half2 bh = __builtin_bit_cast(__half2, b);
    return c + __low2float(ah) * __low2float(bh) + __high2float(ah) * __high2float(bh);
#endif
}

// round-to-nearest-even pack of two floats into f16x2
__device__ __forceinline__ unsigned int packrte(float a, float b) {
    __half2 h = __floats2half2_rn(a, b);
    return __builtin_bit_cast(unsigned int, h);
}

// =====================================================================
// GEMM: C[M,300] = act(A[M,300] @ W[:, :300].T + bias), f16 dot2 inner loop.
// GATHER: A row m = emb[idx[m]] (fp32). APACK: A is packed f16x2 [M, HSTR].
// OMODE: 0 = fp32 full store, 1 = relu + packed-f16x2 store, 2 = maxpool
//        partial (per-block column max -> part[bx*304 + n]).
// Tiles 64x64, K-chunks of 12, 256 threads.
// =====================================================================
template<bool GATHER, bool APACK, bool RELU, int OMODE>
__global__ __launch_bounds__(256) void gemm300h(
    const float* __restrict__ Af, const unsigned int* __restrict__ Ah,
    const int* __restrict__ idx,
    const float* __restrict__ W, int wstride,
    const float* __restrict__ bias,
    float* __restrict__ Cf, unsigned int* __restrict__ Ch)
{
    __shared__ unsigned int As2[6][64];   // [k-pair][m]
    __shared__ unsigned int Bs2[6][64];   // [k-pair][n]
    __shared__ float red[16][68];         // maxpool reduce (OMODE==2)

    const int tid = threadIdx.x;
    const int m0 = blockIdx.x * 64;
    const int n0 = blockIdx.y * 64;

    // loaders: threads 0..191, m_l = tid&63 (consecutive lanes -> conflict-free
    // LDS writes), kq = tid>>6 in {0,1,2} covers 4 k-values each per chunk.
    const float*        afptr = nullptr;
    const unsigned int* ahptr = nullptr;
    const float*        bptr  = nullptr;
    bool bvalid = false;
    int m_l = 0, kq = 0;
    if (tid < 192) {
        m_l = tid & 63;
        kq  = tid >> 6;
        if (GATHER) {
            long row = (long)idx[m0 + m_l];
            afptr = Af + row * 300 + kq * 4;
        } else if (APACK) {
            ahptr = Ah + (long)(m0 + m_l) * HSTR + kq * 2;
        } else {
            afptr = Af + (long)(m0 + m_l) * 300 + kq * 4;
        }
        int j = n0 + m_l;
        bvalid = (j < 300);
        if (bvalid) bptr = W + (long)j * wstride + kq * 4;
    }

    const int ty = tid >> 4;    // 0..15 -> m sub-tile
    const int tx = tid & 15;    // 0..15 -> n sub-tile

    float acc[4][4] = {};

    for (int k0 = 0, kc = 0; k0 < 300; k0 += 12, kc += 6) {
        uint2 av = make_uint2(0u, 0u);
        uint2 bv = make_uint2(0u, 0u);
        if (tid < 192) {
            if (APACK) {
                av = *(const uint2*)(ahptr + kc);
            } else {
                float4 f = *(const float4*)(afptr + k0);
                av.x = packrte(f.x, f.y);
                av.y = packrte(f.z, f.w);
            }
            if (bvalid) {
                float4 g = *(const float4*)(bptr + k0);
                bv.x = packrte(g.x, g.y);
                bv.y = packrte(g.z, g.w);
            }
        }
        __syncthreads();   // previous compute done before overwriting tiles
        if (tid < 192) {
            As2[kq * 2 + 0][m_l] = av.x;
            As2[kq * 2 + 1][m_l] = av.y;
            Bs2[kq * 2 + 0][m_l] = bv.x;
            Bs2[kq * 2 + 1][m_l] = bv.y;
        }
        __syncthreads();

        #pragma unroll
        for (int kp = 0; kp < 6; kp++) {
            uint4 a4 = *(const uint4*)&As2[kp][ty * 4];
            uint4 b4 = *(const uint4*)&Bs2[kp][tx * 4];
            unsigned int aa[4] = {a4.x, a4.y, a4.z, a4.w};
            unsigned int bb[4] = {b4.x, b4.y, b4.z, b4.w};
            #pragma unroll
            for (int im = 0; im < 4; im++)
                #pragma unroll
                for (int in = 0; in < 4; in++)
                    acc[im][in] = dot2(aa[im], bb[in], acc[im][in]);
        }
    }

    // ---- epilogue
    float bsv[4];
    const int nbase = n0 + tx * 4;
    #pragma unroll
    for (int in = 0; in < 4; in++)
        bsv[in] = (nbase + in < 300) ? bias[nbase + in] : 0.f;

    if (OMODE == 0) {
        if (nbase + 3 < 300) {
            #pragma unroll
            for (int im = 0; im < 4; im++) {
                long m = m0 + ty * 4 + im;
                *(float4*)&Cf[m * 300 + nbase] = make_float4(
                    acc[im][0] + bsv[0], acc[im][1] + bsv[1],
                    acc[im][2] + bsv[2], acc[im][3] + bsv[3]);
            }
        }
    } else if (OMODE == 1) {
        if (nbase + 3 < 300) {
            #pragma unroll
            for (int im = 0; im < 4; im++) {
                long m = m0 + ty * 4 + im;
                float v[4];
                #pragma unroll
                for (int in = 0; in < 4; in++) {
                    float x = acc[im][in] + bsv[in];
                    v[in] = RELU ? fmaxf(x, 0.f) : x;
                }
                uint2 pk = make_uint2(packrte(v[0], v[1]), packrte(v[2], v[3]));
                *(uint2*)&Ch[m * HSTR + (nbase >> 1)] = pk;
            }
        }
    } else {  // OMODE == 2: per-block column max -> part
        float vm[4];
        #pragma unroll
        for (int in = 0; in < 4; in++) {
            float m = acc[0][in] + bsv[in];
            #pragma unroll
            for (int im = 1; im < 4; im++)
                m = fmaxf(m, acc[im][in] + bsv[in]);
            vm[in] = m;
        }
        *(float4*)&red[ty][tx * 4] = make_float4(vm[0], vm[1], vm[2], vm[3]);
        __syncthreads();
        if (tid < 64) {
            float m = red[0][tid];
            #pragma unroll
            for (int r = 1; r < 16; r++) m = fmaxf(m, red[r][tid]);
            int n = n0 + tid;
            if (n < 300) Cf[(long)blockIdx.x * 304 + n] = m;
        }
    }
}

// =====================================================================
// RNN: one block per batch element, 960 threads (15 waves).
// Dot stage: 900 threads, thread (j,s) holds Wh[j, s*100:(s+1)*100] as
// 50 packed f16x2 regs; hidden state packed f16x2 in LDS (broadcast reads).
// Reduce stage: 150 threads, 2 outputs each, pack f16x2, prefetched xpart.
// =====================================================================
__global__ __launch_bounds__(960) void rnn_f16(
    const float* __restrict__ xpart,        // [B, T, 300] fp32
    const float* __restrict__ l1_w,         // [300, 600] fp32
    unsigned int* __restrict__ hid_out)     // [B, T, HSTR] packed f16x2
{
    const int b   = blockIdx.x;
    const int tid = threadIdx.x;

    __shared__ unsigned int hidh2[3 * 52];  // per-s stride 52 (16B aligned)
    __shared__ float partial[904];

    // ---- weight preload (fp32 -> packed f16x2, RTE)
    unsigned int wq[50];
    const bool dotact = (tid < 900);
    int s = 0;
    if (dotact) {
        int j = tid / 3;
        s = tid - 3 * j;
        const float4* wr = (const float4*)(l1_w + (long)j * 600 + 300 + s * 100);
        #pragma unroll
        for (int i = 0; i < 25; i++) {
            float4 f = wr[i];
            wq[2 * i + 0] = packrte(f.x, f.y);
            wq[2 * i + 1] = packrte(f.z, f.w);
        }
    }

    const bool redact = (tid < 150);
    const long xb = (long)b * T_SZ * 300;
    const long hb = (long)b * T_SZ * HSTR;
    float2 xp = make_float2(0.f, 0.f);
    if (redact) xp = *(const float2*)(xpart + xb + 2 * tid);   // t=0 prefetch

    if (tid < 156) hidh2[tid] = 0u;   // hidden0 = zeros
    __syncthreads();

    for (int t = 0; t < T_SZ; t++) {
        if (dotact) {
            const uint4* hv = (const uint4*)&hidh2[s * 52];
            float a0 = 0.f, a1 = 0.f, a2 = 0.f, a3 = 0.f;
            #pragma unroll
            for (int i = 0; i < 12; i++) {
                uint4 h4 = hv[i];
                a0 = dot2(wq[4 * i + 0], h4.x, a0);
                a1 = dot2(wq[4 * i + 1], h4.y, a1);
                a2 = dot2(wq[4 * i + 2], h4.z, a2);
                a3 = dot2(wq[4 * i + 3], h4.w, a3);
            }
            {
                uint2 h2v = *(const uint2*)&hidh2[s * 52 + 48];
                a0 = dot2(wq[48], h2v.x, a0);
                a1 = dot2(wq[49], h2v.y, a1);
            }
            partial[tid] = (a0 + a1) + (a2 + a3);
        }
        __syncthreads();

        if (redact) {
            const int p6 = 6 * tid;
            float y0 = xp.x + partial[p6 + 0] + partial[p6 + 1] + partial[p6 + 2];
            float y1 = xp.y + partial[p6 + 3] + partial[p6 + 4] + partial[p6 + 5];
            float h0 = 1.f / (1.f + __expf(-y0));
            float h1 = 1.f / (1.f + __expf(-y1));
            unsigned int pk = packrte(h0, h1);
            hidh2[(tid / 50) * 52 + (tid % 50)] = pk;
            hid_out[hb + (long)t * HSTR + tid] = pk;
            if (t + 1 < T_SZ)   // prefetch next step's additive term
                xp = *(const float2*)(xpart + xb + (long)(t + 1) * 300 + 2 * tid);
        }
        __syncthreads();
    }
}

// =====================================================================
// Final: pooled[b,n] = max over 8 chunks of part; out = pooled @ fc2_w.T + b
// =====================================================================
__global__ __launch_bounds__(320) void fc2_final(
    const float* __restrict__ part,     // [512, 304]
    const float* __restrict__ fc2_w,    // [2, 300]
    const float* __restrict__ fc2_b,    // [2]
    float* __restrict__ out)            // [B, 2]
{
    const int b   = blockIdx.x;
    const int tid = threadIdx.x;
    __shared__ float pooled[304];

    if (tid < 300) {
        float m = part[(long)(b * 8) * 304 + tid];
        #pragma unroll
        for (int c = 1; c < 8; c++)
            m = fmaxf(m, part[(long)(b * 8 + c) * 304 + tid]);
        pooled[tid] = m;
    }
    __syncthreads();

    const int o    = tid >> 6;
    const int lane = tid & 63;
    if (o < 2) {
        float sacc = 0.f;
        for (int jj = lane; jj < 300; jj += 64)
            sacc += pooled[jj] * fc2_w[o * 300 + jj];
        #pragma unroll
        for (int off = 32; off > 0; off >>= 1)
            sacc += __shfl_down(sacc, off);
        if (lane == 0) out[b * 2 + o] = sacc + fc2_b[o];
    }
}

// =====================================================================
extern "C" void kernel_launch(void* const* d_in, const int* in_sizes, int n_in,
                              void* d_out, int out_size, void* d_ws, size_t ws_size,
                              hipStream_t stream)
{
    const int*   x     = (const int*)  d_in[0];
    const float* emb   = (const float*)d_in[1];
    const float* fc1_w = (const float*)d_in[2];
    const float* fc1_b = (const float*)d_in[3];
    const float* l1_w  = (const float*)d_in[4];
    const float* l1_b  = (const float*)d_in[5];
    const float* l2_w  = (const float*)d_in[6];
    const float* l2_b  = (const float*)d_in[7];
    const float* fc2_w = (const float*)d_in[8];
    const float* fc2_b = (const float*)d_in[9];
    float* out = (float*)d_out;

    // workspace (aliased): bufH (packed h, later overwritten by RNN hiddens),
    // bufX (fp32 xpart), part (maxpool partials). Total ~60 MB.
    unsigned int* bufH = (unsigned int*)d_ws;
    float* bufX = (float*)(bufH + (size_t)M_TOT * HSTR);
    float* part = bufX + (size_t)M_TOT * 300;

    dim3 gg(M_TOT / 64, 5), gb(256);

    // K1: h = relu(emb[x] @ fc1_w.T + fc1_b)  -> packed f16x2
    gemm300h<true,  false, true,  1><<<gg, gb, 0, stream>>>(
        emb, nullptr, x, fc1_w, 300, fc1_b, nullptr, bufH);
    // K2: xpart = h @ l1_w[:, :300].T + l1_b  -> fp32
    gemm300h<false, true,  false, 0><<<gg, gb, 0, stream>>>(
        nullptr, bufH, nullptr, l1_w, 600, l1_b, bufX, nullptr);
    // K3: sequential RNN -> packed hiddens (overwrites bufH)
    rnn_f16<<<B_SZ, 960, 0, stream>>>(bufX, l1_w, bufH);
    // K4: outs = hid @ l2_w.T + l2_b, fused per-block max -> part
    gemm300h<false, true,  false, 2><<<gg, gb, 0, stream>>>(
        nullptr, bufH, nullptr, l2_w, 300, l2_b, part, nullptr);
    // K5: final max over chunks + fc2
    fc2_final<<<B_SZ, 320, 0, stream>>>(part, fc2_w, fc2_b, out);
}

// Round 3
// 745.827 us; speedup vs baseline: 1.5850x; 1.0174x over previous
//
#include <hip/hip_runtime.h>
#include <hip/hip_fp16.h>
#include <math.h>

#define B_SZ 64
#define T_SZ 512
#define E_SZ 300
#define M_TOT (B_SZ * T_SZ)   // 32768 tokens
#define HSTR  152             // row stride (uints) of packed-f16x2 buffers (150 used)

typedef _Float16 h2_t __attribute__((ext_vector_type(2)));

// f16-pair dot with fp32 accumulate: c + a.x*b.x + a.y*b.y
__device__ __forceinline__ float dot2(unsigned int a, unsigned int b, float c) {
#if __has_builtin(__builtin_amdgcn_fdot2)
    h2_t ah = __builtin_bit_cast(h2_t, a);
    h2_t bh = __builtin_bit_cast(h2_t, b);
    return __builtin_amdgcn_fdot2(ah, bh, c, false);
#else
    __half2 ah = __builtin_bit_cast(__half2, a);
    __half2 bh = __builtin_bit_cast(__half2, b);
    return c + __low2float(ah) * __low2float(bh) + __high2float(ah) * __high2float(bh);
#endif
}

// round-to-nearest-even pack of two floats into f16x2
__device__ __forceinline__ unsigned int packrte(float a, float b) {
    __half2 h = __floats2half2_rn(a, b);
    return __builtin_bit_cast(unsigned int, h);
}

// =====================================================================
// GEMM: C[M,300] = act(A[M,300] @ W[:, :300].T + bias), f16 dot2 inner loop.
// GATHER: A row m = emb[idx[m]] (fp32). APACK: A is packed f16x2 [M, HSTR].
// OMODE: 0 = fp32 full store, 1 = relu + packed-f16x2 store, 2 = maxpool
//        partial (per-block column max -> part[bx*304 + n]).
// Tiles 64x64, K-chunks of 12, 256 threads.
// =====================================================================
template<bool GATHER, bool APACK, bool RELU, int OMODE>
__global__ __launch_bounds__(256) void gemm300h(
    const float* __restrict__ Af, const unsigned int* __restrict__ Ah,
    const int* __restrict__ idx,
    const float* __restrict__ W, int wstride,
    const float* __restrict__ bias,
    float* __restrict__ Cf, unsigned int* __restrict__ Ch)
{
    __shared__ unsigned int As2[6][64];   // [k-pair][m]
    __shared__ unsigned int Bs2[6][64];   // [k-pair][n]
    __shared__ float red[16][68];         // maxpool reduce (OMODE==2)

    const int tid = threadIdx.x;
    const int m0 = blockIdx.x * 64;
    const int n0 = blockIdx.y * 64;

    const float*        afptr = nullptr;
    const unsigned int* ahptr = nullptr;
    const float*        bptr  = nullptr;
    bool bvalid = false;
    int m_l = 0, kq = 0;
    if (tid < 192) {
        m_l = tid & 63;
        kq  = tid >> 6;
        if (GATHER) {
            long row = (long)idx[m0 + m_l];
            afptr = Af + row * 300 + kq * 4;
        } else if (APACK) {
            ahptr = Ah + (long)(m0 + m_l) * HSTR + kq * 2;
        } else {
            afptr = Af + (long)(m0 + m_l) * 300 + kq * 4;
        }
        int j = n0 + m_l;
        bvalid = (j < 300);
        if (bvalid) bptr = W + (long)j * wstride + kq * 4;
    }

    const int ty = tid >> 4;
    const int tx = tid & 15;

    float acc[4][4] = {};

    for (int k0 = 0, kc = 0; k0 < 300; k0 += 12, kc += 6) {
        uint2 av = make_uint2(0u, 0u);
        uint2 bv = make_uint2(0u, 0u);
        if (tid < 192) {
            if (APACK) {
                av = *(const uint2*)(ahptr + kc);
            } else {
                float4 f = *(const float4*)(afptr + k0);
                av.x = packrte(f.x, f.y);
                av.y = packrte(f.z, f.w);
            }
            if (bvalid) {
                float4 g = *(const float4*)(bptr + k0);
                bv.x = packrte(g.x, g.y);
                bv.y = packrte(g.z, g.w);
            }
        }
        __syncthreads();
        if (tid < 192) {
            As2[kq * 2 + 0][m_l] = av.x;
            As2[kq * 2 + 1][m_l] = av.y;
            Bs2[kq * 2 + 0][m_l] = bv.x;
            Bs2[kq * 2 + 1][m_l] = bv.y;
        }
        __syncthreads();

        #pragma unroll
        for (int kp = 0; kp < 6; kp++) {
            uint4 a4 = *(const uint4*)&As2[kp][ty * 4];
            uint4 b4 = *(const uint4*)&Bs2[kp][tx * 4];
            unsigned int aa[4] = {a4.x, a4.y, a4.z, a4.w};
            unsigned int bb[4] = {b4.x, b4.y, b4.z, b4.w};
            #pragma unroll
            for (int im = 0; im < 4; im++)
                #pragma unroll
                for (int in = 0; in < 4; in++)
                    acc[im][in] = dot2(aa[im], bb[in], acc[im][in]);
        }
    }

    float bsv[4];
    const int nbase = n0 + tx * 4;
    #pragma unroll
    for (int in = 0; in < 4; in++)
        bsv[in] = (nbase + in < 300) ? bias[nbase + in] : 0.f;

    if (OMODE == 0) {
        if (nbase + 3 < 300) {
            #pragma unroll
            for (int im = 0; im < 4; im++) {
                long m = m0 + ty * 4 + im;
                *(float4*)&Cf[m * 300 + nbase] = make_float4(
                    acc[im][0] + bsv[0], acc[im][1] + bsv[1],
                    acc[im][2] + bsv[2], acc[im][3] + bsv[3]);
            }
        }
    } else if (OMODE == 1) {
        if (nbase + 3 < 300) {
            #pragma unroll
            for (int im = 0; im < 4; im++) {
                long m = m0 + ty * 4 + im;
                float v[4];
                #pragma unroll
                for (int in = 0; in < 4; in++) {
                    float x = acc[im][in] + bsv[in];
                    v[in] = RELU ? fmaxf(x, 0.f) : x;
                }
                uint2 pk = make_uint2(packrte(v[0], v[1]), packrte(v[2], v[3]));
                *(uint2*)&Ch[m * HSTR + (nbase >> 1)] = pk;
            }
        }
    } else {  // OMODE == 2: per-block column max -> part
        float vm[4];
        #pragma unroll
        for (int in = 0; in < 4; in++) {
            float m = acc[0][in] + bsv[in];
            #pragma unroll
            for (int im = 1; im < 4; im++)
                m = fmaxf(m, acc[im][in] + bsv[in]);
            vm[in] = m;
        }
        *(float4*)&red[ty][tx * 4] = make_float4(vm[0], vm[1], vm[2], vm[3]);
        __syncthreads();
        if (tid < 64) {
            float m = red[0][tid];
            #pragma unroll
            for (int r = 1; r < 16; r++) m = fmaxf(m, red[r][tid]);
            int n = n0 + tid;
            if (n < 300) Cf[(long)blockIdx.x * 304 + n] = m;
        }
    }
}

// =====================================================================
// RNN v3: one block (512 threads) per batch element.
// Dot stage: 450 threads; thread (g,s) g in [0,75), s in [0,6) owns
// outputs 4g..4g+3 over k-slice [50s, 50s+50): 100 weight uints in
// registers, reads its 25-uint h-slice from LDS (wave ~same s -> broadcast,
// 7 LDS inst for 100 dot2), writes ONE float4 partial.
// Reduce stage: 300 threads, 1 output each: 6 coalesced b32 partial reads,
// sigmoid, b16 write of h into slice-layout LDS + global f16 store.
// =====================================================================
__global__ __launch_bounds__(512) void rnn_v3(
    const float* __restrict__ xpart,        // [B, T, 300] fp32
    const float* __restrict__ l1_w,         // [300, 600] fp32
    unsigned int* __restrict__ hid_out)     // [B, T, HSTR] packed f16x2
{
    const int b   = blockIdx.x;
    const int tid = threadIdx.x;

    // h slices: slice s at uints [28s, 28s+25): pair i = (h[50s+2i], h[50s+2i+1])
    __shared__ unsigned int hidh2[6 * 28];     // 168 uints
    __shared__ float partial[6][304];

    const bool dotact = (tid < 450);
    const int g = tid % 75;
    const int s = tid / 75;    // 0..5 for active threads

    // ---- weight preload: wq[o][i] = packed (W[4g+o][300+50s+2i], ...+2i+1)
    unsigned int wq[4][25];
    if (dotact) {
        #pragma unroll
        for (int o = 0; o < 4; o++) {
            const float2* wr = (const float2*)(l1_w + (long)(4 * g + o) * 600 + 300 + 50 * s);
            #pragma unroll
            for (int i = 0; i < 25; i++) {
                float2 f = wr[i];
                wq[o][i] = packrte(f.x, f.y);
            }
        }
    }

    const bool redact = (tid < 300);
    const long xb = (long)b * T_SZ * 300;
    __half* hid_out_h = (__half*)(hid_out + (long)b * T_SZ * HSTR);

    float xp = 0.f;
    if (redact) xp = xpart[xb + tid];   // t=0 prefetch

    if (tid < 168) hidh2[tid] = 0u;     // hidden0 = zeros
    __syncthreads();

    for (int t = 0; t < T_SZ; t++) {
        if (dotact) {
            const uint4* hv = (const uint4*)&hidh2[28 * s];
            const unsigned int hlast = hidh2[28 * s + 24];
            float a0 = 0.f, a1 = 0.f, a2 = 0.f, a3 = 0.f;
            #pragma unroll
            for (int i = 0; i < 6; i++) {
                uint4 h4 = hv[i];
                a0 = dot2(wq[0][4 * i + 0], h4.x, a0);
                a1 = dot2(wq[1][4 * i + 0], h4.x, a1);
                a2 = dot2(wq[2][4 * i + 0], h4.x, a2);
                a3 = dot2(wq[3][4 * i + 0], h4.x, a3);
                a0 = dot2(wq[0][4 * i + 1], h4.y, a0);
                a1 = dot2(wq[1][4 * i + 1], h4.y, a1);
                a2 = dot2(wq[2][4 * i + 1], h4.y, a2);
                a3 = dot2(wq[3][4 * i + 1], h4.y, a3);
                a0 = dot2(wq[0][4 * i + 2], h4.z, a0);
                a1 = dot2(wq[1][4 * i + 2], h4.z, a1);
                a2 = dot2(wq[2][4 * i + 2], h4.z, a2);
                a3 = dot2(wq[3][4 * i + 2], h4.z, a3);
                a0 = dot2(wq[0][4 * i + 3], h4.w, a0);
                a1 = dot2(wq[1][4 * i + 3], h4.w, a1);
                a2 = dot2(wq[2][4 * i + 3], h4.w, a2);
                a3 = dot2(wq[3][4 * i + 3], h4.w, a3);
            }
            a0 = dot2(wq[0][24], hlast, a0);
            a1 = dot2(wq[1][24], hlast, a1);
            a2 = dot2(wq[2][24], hlast, a2);
            a3 = dot2(wq[3][24], hlast, a3);
            *(float4*)&partial[s][4 * g] = make_float4(a0, a1, a2, a3);
        }
        __syncthreads();

        if (redact) {
            float y = xp
                + ((partial[0][tid] + partial[1][tid]) + (partial[2][tid] + partial[3][tid]))
                + (partial[4][tid] + partial[5][tid]);
            float h = 1.f / (1.f + __expf(-y));
            __half hh = __float2half_rn(h);
            // LDS slice write: value j=tid -> slice tid/50, halves stride 56
            ((__half*)hidh2)[(tid / 50) * 56 + (tid % 50)] = hh;
            // global packed-f16 row (stride 304 halves = HSTR uints)
            hid_out_h[(long)t * 304 + tid] = hh;
            if (t + 1 < T_SZ)
                xp = xpart[xb + (long)(t + 1) * 300 + tid];
        }
        __syncthreads();
    }
}

// =====================================================================
// Final: pooled[b,n] = max over 8 chunks of part; out = pooled @ fc2_w.T + b
// =====================================================================
__global__ __launch_bounds__(320) void fc2_final(
    const float* __restrict__ part,     // [512, 304]
    const float* __restrict__ fc2_w,    // [2, 300]
    const float* __restrict__ fc2_b,    // [2]
    float* __restrict__ out)            // [B, 2]
{
    const int b   = blockIdx.x;
    const int tid = threadIdx.x;
    __shared__ float pooled[304];

    if (tid < 300) {
        float m = part[(long)(b * 8) * 304 + tid];
        #pragma unroll
        for (int c = 1; c < 8; c++)
            m = fmaxf(m, part[(long)(b * 8 + c) * 304 + tid]);
        pooled[tid] = m;
    }
    __syncthreads();

    const int o    = tid >> 6;
    const int lane = tid & 63;
    if (o < 2) {
        float sacc = 0.f;
        for (int jj = lane; jj < 300; jj += 64)
            sacc += pooled[jj] * fc2_w[o * 300 + jj];
        #pragma unroll
        for (int off = 32; off > 0; off >>= 1)
            sacc += __shfl_down(sacc, off);
        if (lane == 0) out[b * 2 + o] = sacc + fc2_b[o];
    }
}

// =====================================================================
extern "C" void kernel_launch(void* const* d_in, const int* in_sizes, int n_in,
                              void* d_out, int out_size, void* d_ws, size_t ws_size,
                              hipStream_t stream)
{
    const int*   x     = (const int*)  d_in[0];
    const float* emb   = (const float*)d_in[1];
    const float* fc1_w = (const float*)d_in[2];
    const float* fc1_b = (const float*)d_in[3];
    const float* l1_w  = (const float*)d_in[4];
    const float* l1_b  = (const float*)d_in[5];
    const float* l2_w  = (const float*)d_in[6];
    const float* l2_b  = (const float*)d_in[7];
    const float* fc2_w = (const float*)d_in[8];
    const float* fc2_b = (const float*)d_in[9];
    float* out = (float*)d_out;

    unsigned int* bufH = (unsigned int*)d_ws;
    float* bufX = (float*)(bufH + (size_t)M_TOT * HSTR);
    float* part = bufX + (size_t)M_TOT * 300;

    dim3 gg(M_TOT / 64, 5), gb(256);

    // K1: h = relu(emb[x] @ fc1_w.T + fc1_b)  -> packed f16x2
    gemm300h<true,  false, true,  1><<<gg, gb, 0, stream>>>(
        emb, nullptr, x, fc1_w, 300, fc1_b, nullptr, bufH);
    // K2: xpart = h @ l1_w[:, :300].T + l1_b  -> fp32
    gemm300h<false, true,  false, 0><<<gg, gb, 0, stream>>>(
        nullptr, bufH, nullptr, l1_w, 600, l1_b, bufX, nullptr);
    // K3: sequential RNN -> packed hiddens (overwrites bufH)
    rnn_v3<<<B_SZ, 512, 0, stream>>>(bufX, l1_w, bufH);
    // K4: outs = hid @ l2_w.T + l2_b, fused per-block max -> part
    gemm300h<false, true,  false, 2><<<gg, gb, 0, stream>>>(
        nullptr, bufH, nullptr, l2_w, 300, l2_b, part, nullptr);
    // K5: final max over chunks + fc2
    fc2_final<<<B_SZ, 320, 0, stream>>>(part, fc2_w, fc2_b, out);
}

// Round 4
// 641.276 us; speedup vs baseline: 1.8435x; 1.1630x over previous
//
#include <hip/hip_runtime.h>
#include <hip/hip_fp16.h>
#include <math.h>

#define B_SZ 64
#define T_SZ 512
#define E_SZ 300
#define M_TOT (B_SZ * T_SZ)   // 32768 tokens
#define HSTR  152             // row stride (uints) of packed-f16x2 buffers (304 halves)

typedef _Float16 f16x8 __attribute__((ext_vector_type(8)));
typedef float    f32x4 __attribute__((ext_vector_type(4)));
typedef _Float16 h2_t  __attribute__((ext_vector_type(2)));

// f16-pair dot with fp32 accumulate
__device__ __forceinline__ float dot2(unsigned int a, unsigned int b, float c) {
#if __has_builtin(__builtin_amdgcn_fdot2)
    h2_t ah = __builtin_bit_cast(h2_t, a);
    h2_t bh = __builtin_bit_cast(h2_t, b);
    return __builtin_amdgcn_fdot2(ah, bh, c, false);
#else
    __half2 ah = __builtin_bit_cast(__half2, a);
    __half2 bh = __builtin_bit_cast(__half2, b);
    return c + __low2float(ah) * __low2float(bh) + __high2float(ah) * __high2float(bh);
#endif
}

__device__ __forceinline__ unsigned int packrte(float a, float b) {
    __half2 h = __floats2half2_rn(a, b);
    return __builtin_bit_cast(unsigned int, h);
}

// =====================================================================
// W fp32 -> packed f16x2, K padded to 320 halves (160 uints), zero tail.
// grid (300, 3), 160 threads. Wh layout: [mat][300][160 uints]
// =====================================================================
__global__ __launch_bounds__(160) void wconv(
    const float* __restrict__ fc1_w, const float* __restrict__ l1_w,
    const float* __restrict__ l2_w, unsigned int* __restrict__ Wh)
{
    const int r = blockIdx.x, m = blockIdx.y, j = threadIdx.x;
    const float* src; int stride;
    if (m == 0)      { src = fc1_w; stride = 300; }
    else if (m == 1) { src = l1_w;  stride = 600; }   // x-part cols 0..299
    else             { src = l2_w;  stride = 300; }
    int k = 2 * j;
    float a = (k < 300) ? src[(long)r * stride + k]     : 0.f;
    float b = (k < 300) ? src[(long)r * stride + k + 1] : 0.f;  // 300 even
    Wh[((long)m * 300 + r) * 160 + j] = packrte(a, b);
}

// =====================================================================
// MFMA GEMM: C[M,300] = A[M,300] @ W.T + bias  (f16 inputs, fp32 acc)
// Block tile 64(M) x 160(N), K-chunks of 32 (10 chunks, K padded to 320).
// 256 threads = 4 waves; wave w owns rows 16w..16w+15, all 10 n-frags.
// GATHER: A row m = emb[idx[m]] fp32 (convert in staging).
// else:   A = packed f16 [M][152 uints] (pads uints 150/151 zeroed by producer).
// OMODE: 0 = +bias, fp32 store;  1 = +bias, relu, f16 store (+pad zeros);
//        2 = +bias, max over 64 rows -> part[bx*320 + n]
// =====================================================================
template<bool GATHER, int OMODE>
__global__ __launch_bounds__(256) void mfma_gemm(
    const float* __restrict__ embA, const unsigned int* __restrict__ Ah,
    const int* __restrict__ idx,
    const unsigned int* __restrict__ Wh,   // [300][160] packed f16x2
    const float* __restrict__ bias,
    float* __restrict__ Cf, __half* __restrict__ Chh)
{
    __shared__ _Float16 At[64 * 40];    // row stride 40 halves (80 B)
    __shared__ _Float16 Bt[160 * 40];
    __shared__ float red[4][160];

    const int tid  = threadIdx.x;
    const int m0   = blockIdx.x * 64;
    const int n0   = blockIdx.y * 160;
    const int w    = tid >> 6;
    const int lane = tid & 63;
    const int ml   = lane & 15;
    const int q    = lane >> 4;

    // A staging: thread t -> row t>>2, part t&3 (8 halves each)
    const int ar = tid >> 2, ap = tid & 3;
    const float*        embrow = nullptr;
    const unsigned int* arow   = nullptr;
    if (GATHER) embrow = embA + (long)idx[m0 + ar] * 300;
    else        arow   = Ah + (long)(m0 + ar) * HSTR;

    f32x4 acc[10];
    #pragma unroll
    for (int i = 0; i < 10; i++) acc[i] = (f32x4){0.f, 0.f, 0.f, 0.f};

    #pragma unroll 1
    for (int kc = 0; kc < 10; kc++) {
        // ---- load A piece to regs
        uint4 aval;
        if (GATHER) {
            int k = kc * 32 + ap * 8;
            float4 f0 = (k < 300)     ? *(const float4*)(embrow + k)     : make_float4(0,0,0,0);
            float4 f1 = (k + 4 < 300) ? *(const float4*)(embrow + k + 4) : make_float4(0,0,0,0);
            aval = make_uint4(packrte(f0.x, f0.y), packrte(f0.z, f0.w),
                              packrte(f1.x, f1.y), packrte(f1.z, f1.w));
        } else {
            int u = kc * 16 + ap * 4;
            aval = (u <= 148) ? *(const uint4*)(arow + u) : make_uint4(0, 0, 0, 0);
        }
        // ---- load B pieces to regs (640 uint4 over 256 threads)
        uint4 bval[3];
        #pragma unroll
        for (int jj = 0; jj < 3; jj++) {
            int i = tid + jj * 256;
            if (i < 640) {
                int row = i >> 2, quad = i & 3;
                int n = n0 + row;
                bval[jj] = (n < 300)
                    ? *(const uint4*)(Wh + (long)n * 160 + kc * 16 + quad * 4)
                    : make_uint4(0, 0, 0, 0);
            }
        }
        __syncthreads();   // prev chunk's frag reads done
        *(uint4*)&At[ar * 40 + ap * 8] = aval;
        #pragma unroll
        for (int jj = 0; jj < 3; jj++) {
            int i = tid + jj * 256;
            if (i < 640) {
                int row = i >> 2, quad = i & 3;
                *(uint4*)&Bt[row * 40 + quad * 8] = bval[jj];
            }
        }
        __syncthreads();

        // ---- MFMA: A[m=lane&15][k=q*8+j], B[n=lane&15][k=q*8+j]
        f16x8 af = *(const f16x8*)&At[(16 * w + ml) * 40 + q * 8];
        #pragma unroll
        for (int fi = 0; fi < 10; fi++) {
            f16x8 bf = *(const f16x8*)&Bt[(fi * 16 + ml) * 40 + q * 8];
            acc[fi] = __builtin_amdgcn_mfma_f32_16x16x32_f16(af, bf, acc[fi], 0, 0, 0);
        }
    }

    // ---- epilogue.  D: row m = 16w + q*4 + r, col n = n0 + fi*16 + ml
    if (OMODE == 0 || OMODE == 1) {
        #pragma unroll
        for (int fi = 0; fi < 10; fi++) {
            int col = n0 + fi * 16 + ml;
            float bv = (col < 300) ? bias[col] : 0.f;
            #pragma unroll
            for (int r = 0; r < 4; r++) {
                long m = m0 + 16 * w + q * 4 + r;
                float v = acc[fi][r] + bv;
                if (OMODE == 0) {
                    if (col < 300) Cf[m * 300 + col] = v;
                } else {
                    if (col < 300)      Chh[m * 304 + col] = __float2half_rn(fmaxf(v, 0.f));
                    else if (col < 304) Chh[m * 304 + col] = __float2half_rn(0.f);  // pad
                }
            }
        }
    } else {   // OMODE == 2: column max over the 64-row tile
        #pragma unroll
        for (int fi = 0; fi < 10; fi++) {
            float v = fmaxf(fmaxf(acc[fi][0], acc[fi][1]), fmaxf(acc[fi][2], acc[fi][3]));
            v = fmaxf(v, __shfl_xor(v, 16));
            v = fmaxf(v, __shfl_xor(v, 32));
            if (lane < 16) red[w][fi * 16 + lane] = v;
        }
        __syncthreads();
        if (tid < 160) {
            int col = n0 + tid;
            if (col < 300) {
                float v = fmaxf(fmaxf(red[0][tid], red[1][tid]),
                                fmaxf(red[2][tid], red[3][tid]));
                Cf[(long)blockIdx.x * 320 + col] = v + bias[col];
            }
        }
    }
}

// =====================================================================
// RNN v4: one block (512 thr) per batch element. 16-step chunks:
// xpart chunk (19.2 KB fp32) double-buffered in LDS (reg-carried prefetch
// issued at chunk start -> one vmcnt drain per 16 steps); h outputs
// buffered in LDS, flushed per chunk as uint4 stores. In-loop barriers
// drain only LDS ops.
// Dot stage: 450 thr, thread (g,s) owns outputs 4g..4g+3 over k-slice
// [50s,50s+50): 100 weight uints in regs, broadcast LDS h reads.
// =====================================================================
__global__ __launch_bounds__(512) void rnn_v4(
    const float* __restrict__ xpart,        // [B, T, 300] fp32
    const float* __restrict__ l1_w,         // [300, 600] fp32
    unsigned int* __restrict__ hid_out)     // [B, T, HSTR] packed f16x2
{
    const int b   = blockIdx.x;
    const int tid = threadIdx.x;

    __shared__ float xbuf[2][4800];            // 16 steps x 300 fp32, x2
    __shared__ unsigned int hidh2[168];        // h slices: s at [28s,28s+25)
    __shared__ float partial[6][304];
    __shared__ __half hbuf[16 * 304];          // chunk h output (pad zeroed)

    const bool dotact = (tid < 450);
    const int g = tid % 75;
    const int s = tid / 75;

    // ---- weight preload: wq[o][i] = packed (W[4g+o][300+50s+2i], +2i+1)
    unsigned int wq[4][25];
    if (dotact) {
        #pragma unroll
        for (int o = 0; o < 4; o++) {
            const float2* wr = (const float2*)(l1_w + (long)(4 * g + o) * 600 + 300 + 50 * s);
            #pragma unroll
            for (int i = 0; i < 25; i++) {
                float2 f = wr[i];
                wq[o][i] = packrte(f.x, f.y);
            }
        }
    }

    const float4* xsrc = (const float4*)(xpart + (long)b * T_SZ * 300);  // 38400 float4
    uint4* gout = (uint4*)(hid_out + (long)b * T_SZ * HSTR);

    // ---- preload chunk 0
    float4 pf[3];
    #pragma unroll
    for (int j = 0; j < 3; j++) {
        int i = tid + j * 512;
        if (i < 1200) pf[j] = xsrc[i];
    }
    #pragma unroll
    for (int j = 0; j < 3; j++) {
        int i = tid + j * 512;
        if (i < 1200) *(float4*)&xbuf[0][i * 4] = pf[j];
    }
    if (tid < 168) hidh2[tid] = 0u;
    __syncthreads();

    #pragma unroll 1
    for (int c = 0; c < 32; c++) {
        const float* xc = xbuf[c & 1];
        const bool pf_on = (c + 1 < 32);
        if (pf_on) {   // issue prefetch; drained at first in-chunk barrier
            #pragma unroll
            for (int j = 0; j < 3; j++) {
                int i = tid + j * 512;
                if (i < 1200) pf[j] = xsrc[(c + 1) * 1200 + i];
            }
        }

        #pragma unroll 1
        for (int st = 0; st < 16; st++) {
            if (dotact) {
                const uint4* hv = (const uint4*)&hidh2[28 * s];
                const unsigned int hlast = hidh2[28 * s + 24];
                float a0 = 0.f, a1 = 0.f, a2 = 0.f, a3 = 0.f;
                #pragma unroll
                for (int i = 0; i < 6; i++) {
                    uint4 h4 = hv[i];
                    a0 = dot2(wq[0][4 * i + 0], h4.x, a0);
                    a1 = dot2(wq[1][4 * i + 0], h4.x, a1);
                    a2 = dot2(wq[2][4 * i + 0], h4.x, a2);
                    a3 = dot2(wq[3][4 * i + 0], h4.x, a3);
                    a0 = dot2(wq[0][4 * i + 1], h4.y, a0);
                    a1 = dot2(wq[1][4 * i + 1], h4.y, a1);
                    a2 = dot2(wq[2][4 * i + 1], h4.y, a2);
                    a3 = dot2(wq[3][4 * i + 1], h4.y, a3);
                    a0 = dot2(wq[0][4 * i + 2], h4.z, a0);
                    a1 = dot2(wq[1][4 * i + 2], h4.z, a1);
                    a2 = dot2(wq[2][4 * i + 2], h4.z, a2);
                    a3 = dot2(wq[3][4 * i + 2], h4.z, a3);
                    a0 = dot2(wq[0][4 * i + 3], h4.w, a0);
                    a1 = dot2(wq[1][4 * i + 3], h4.w, a1);
                    a2 = dot2(wq[2][4 * i + 3], h4.w, a2);
                    a3 = dot2(wq[3][4 * i + 3], h4.w, a3);
                }
                a0 = dot2(wq[0][24], hlast, a0);
                a1 = dot2(wq[1][24], hlast, a1);
                a2 = dot2(wq[2][24], hlast, a2);
                a3 = dot2(wq[3][24], hlast, a3);
                *(float4*)&partial[s][4 * g] = make_float4(a0, a1, a2, a3);
            }
            __syncthreads();

            if (tid < 304) {
                if (tid < 300) {
                    float y = xc[st * 300 + tid]
                        + ((partial[0][tid] + partial[1][tid]) + (partial[2][tid] + partial[3][tid]))
                        + (partial[4][tid] + partial[5][tid]);
                    float h = 1.f / (1.f + __expf(-y));
                    __half hh = __float2half_rn(h);
                    ((__half*)hidh2)[(tid / 50) * 56 + (tid % 50)] = hh;
                    hbuf[st * 304 + tid] = hh;
                } else {
                    hbuf[st * 304 + tid] = __float2half_rn(0.f);   // keep pad zero
                }
            }
            __syncthreads();
        }

        // ---- commit prefetched chunk to the other buffer
        if (pf_on) {
            #pragma unroll
            for (int j = 0; j < 3; j++) {
                int i = tid + j * 512;
                if (i < 1200) *(float4*)&xbuf[(c + 1) & 1][i * 4] = pf[j];
            }
        }
        // ---- flush hbuf: 16 rows x 152 uints = 608 uint4, contiguous
        const uint4* hb4 = (const uint4*)hbuf;
        for (int i = tid; i < 608; i += 512) gout[c * 608 + i] = hb4[i];
    }
}

// =====================================================================
// Final: pooled[b,n] = max over 8 m-chunks of part; out = pooled @ fc2_w.T
// =====================================================================
__global__ __launch_bounds__(320) void fc2_final(
    const float* __restrict__ part,     // [512, 320]
    const float* __restrict__ fc2_w,
    const float* __restrict__ fc2_b,
    float* __restrict__ out)
{
    const int b   = blockIdx.x;
    const int tid = threadIdx.x;
    __shared__ float pooled[304];

    if (tid < 300) {
        float m = part[(long)(b * 8) * 320 + tid];
        #pragma unroll
        for (int c = 1; c < 8; c++)
            m = fmaxf(m, part[(long)(b * 8 + c) * 320 + tid]);
        pooled[tid] = m;
    }
    __syncthreads();

    const int o    = tid >> 6;
    const int lane = tid & 63;
    if (o < 2) {
        float sacc = 0.f;
        for (int jj = lane; jj < 300; jj += 64)
            sacc += pooled[jj] * fc2_w[o * 300 + jj];
        #pragma unroll
        for (int off = 32; off > 0; off >>= 1)
            sacc += __shfl_down(sacc, off);
        if (lane == 0) out[b * 2 + o] = sacc + fc2_b[o];
    }
}

// =====================================================================
extern "C" void kernel_launch(void* const* d_in, const int* in_sizes, int n_in,
                              void* d_out, int out_size, void* d_ws, size_t ws_size,
                              hipStream_t stream)
{
    const int*   x     = (const int*)  d_in[0];
    const float* emb   = (const float*)d_in[1];
    const float* fc1_w = (const float*)d_in[2];
    const float* fc1_b = (const float*)d_in[3];
    const float* l1_w  = (const float*)d_in[4];
    const float* l1_b  = (const float*)d_in[5];
    const float* l2_w  = (const float*)d_in[6];
    const float* l2_b  = (const float*)d_in[7];
    const float* fc2_w = (const float*)d_in[8];
    const float* fc2_b = (const float*)d_in[9];
    float* out = (float*)d_out;

    // ws layout: bufH (19.9 MB) | bufX (39.3 MB) | part (0.66 MB) | Wh (0.58 MB)
    unsigned int* bufH = (unsigned int*)d_ws;
    float* bufX = (float*)(bufH + (size_t)M_TOT * HSTR);
    float* part = bufX + (size_t)M_TOT * 300;
    unsigned int* WhAll = (unsigned int*)(part + (size_t)512 * 320);
    unsigned int* W1h = WhAll;
    unsigned int* W2h = WhAll + (size_t)300 * 160;
    unsigned int* W3h = WhAll + (size_t)2 * 300 * 160;

    // K0: weights fp32 -> f16, K padded to 320
    wconv<<<dim3(300, 3), 160, 0, stream>>>(fc1_w, l1_w, l2_w, WhAll);
    // K1: h = relu(emb[x] @ fc1_w.T + fc1_b) -> packed f16 (pads zeroed)
    mfma_gemm<true, 1><<<dim3(512, 2), 256, 0, stream>>>(
        emb, nullptr, x, W1h, fc1_b, nullptr, (__half*)bufH);
    // K2: xpart = h @ l1_w[:, :300].T + l1_b -> fp32
    mfma_gemm<false, 0><<<dim3(512, 2), 256, 0, stream>>>(
        nullptr, bufH, nullptr, W2h, l1_b, bufX, nullptr);
    // K3: sequential RNN -> packed hiddens (overwrites bufH)
    rnn_v4<<<B_SZ, 512, 0, stream>>>(bufX, l1_w, bufH);
    // K4: outs = hid @ l2_w.T + l2_b, fused 64-row max -> part
    mfma_gemm<false, 2><<<dim3(512, 2), 256, 0, stream>>>(
        nullptr, bufH, nullptr, W3h, l2_b, part, nullptr);
    // K5: final max over chunks + fc2
    fc2_final<<<B_SZ, 320, 0, stream>>>(part, fc2_w, fc2_b, out);
}